// Round 3
// baseline (2214.031 us; speedup 1.0000x reference)
//
#include <hip/hip_runtime.h>
#include <hip/hip_bf16.h>
#include <math.h>

typedef __hip_bfloat16 bf16;
typedef __attribute__((ext_vector_type(8))) short s8v;   // 8 x bf16 bits
typedef __attribute__((ext_vector_type(4))) short s4v;   // 4 x bf16 bits
typedef __attribute__((ext_vector_type(4))) float f4v;   // MFMA accumulator

static __device__ __forceinline__ float bfs2f(short s) {
    return __uint_as_float(((unsigned)(unsigned short)s) << 16);
}
static __device__ __forceinline__ short f2bfs(float f) {
    __hip_bfloat16 h = __float2bfloat16(f);
    return *reinterpret_cast<short*>(&h);
}

// ---------------------------------------------------------------------------
// fp32 -> bf16 conversion (vectorized x4).
// ---------------------------------------------------------------------------
__global__ __launch_bounds__(256)
void cvt_f32_bf16(const float* __restrict__ in, bf16* __restrict__ out, long n4)
{
    const long i = (long)blockIdx.x * 256 + threadIdx.x;
    if (i >= n4) return;
    const float4 v = reinterpret_cast<const float4*>(in)[i];
    s4v o;
    o[0] = f2bfs(v.x); o[1] = f2bfs(v.y); o[2] = f2bfs(v.z); o[3] = f2bfs(v.w);
    reinterpret_cast<s4v*>(out)[i] = o;
}

// ---------------------------------------------------------------------------
// GEMM: C[M,N](bf16) = act(A[M,K] @ B[N,K]^T + bias[N])
// m97 structure: 128x128 tile, BK=32, 256 threads (4 waves, 2x2 of 64x64),
// global_load_lds width-16 staging, mfma_f32_16x16x32_bf16.
// M = gridDim.x*128, N = gridDim.y*128. A row-major stride K, B row-major [N,K].
// bias fp32. Writes C[r*ldc + coff + n].
// ---------------------------------------------------------------------------
template<int ACT>
__global__ __launch_bounds__(256)
void gemm_bt(const bf16* __restrict__ A, const bf16* __restrict__ B,
             const float* __restrict__ bias, bf16* __restrict__ C,
             int K, int ldc, int coff)
{
    __shared__ __align__(16) bf16 sA[128 * 32];
    __shared__ __align__(16) bf16 sB[128 * 32];
    const int tid  = threadIdx.x;
    const int lane = tid & 63;
    const int bRow = blockIdx.x;
    const int bCol = blockIdx.y;
    const int wr = ((tid >> 7) & 1) * 64;  // wave row (2x2 wave grid)
    const int wc = ((tid >> 6) & 1) * 64;  // wave col

    f4v acc[4][4];
#pragma unroll
    for (int i = 0; i < 4; ++i)
#pragma unroll
        for (int j = 0; j < 4; ++j) acc[i][j] = (f4v)(0.0f);

    // staging: thread t loads 16B chunk; row = p*64 + t/4, chunk col = (t&3)*8
    const int ldrow = tid >> 2;
    const int ldcol = (tid & 3) * 8;
    const bf16* Ab = A + (long)bRow * 128 * K + (long)ldrow * K + ldcol;
    const bf16* Bb = B + (long)bCol * 128 * K + (long)ldrow * K + ldcol;
    const int ldsWB = (tid & 192) * 16;  // wave-uniform LDS byte base (wave*1024)
    char* sAc = (char*)sA;
    char* sBc = (char*)sB;

    const int nk = K >> 5;
    for (int kt = 0; kt < nk; ++kt) {
        const int k0 = kt << 5;
        __syncthreads();
#pragma unroll
        for (int p = 0; p < 2; ++p) {
            __builtin_amdgcn_global_load_lds(
                (const __attribute__((address_space(1))) unsigned int*)(Ab + (long)(p * 64) * K + k0),
                (__attribute__((address_space(3))) unsigned int*)(sAc + p * 4096 + ldsWB),
                16, 0, 0);
            __builtin_amdgcn_global_load_lds(
                (const __attribute__((address_space(1))) unsigned int*)(Bb + (long)(p * 64) * K + k0),
                (__attribute__((address_space(3))) unsigned int*)(sBc + p * 4096 + ldsWB),
                16, 0, 0);
        }
        __syncthreads();
        const int fr  = lane & 15;
        const int kb8 = (lane >> 4) * 8;
        s8v af[4], bfr[4];
#pragma unroll
        for (int mi = 0; mi < 4; ++mi)
            af[mi] = *(const s8v*)(&sA[(wr + mi * 16 + fr) * 32 + kb8]);
#pragma unroll
        for (int ni = 0; ni < 4; ++ni)
            bfr[ni] = *(const s8v*)(&sB[(wc + ni * 16 + fr) * 32 + kb8]);
#pragma unroll
        for (int mi = 0; mi < 4; ++mi)
#pragma unroll
            for (int ni = 0; ni < 4; ++ni)
                acc[mi][ni] = __builtin_amdgcn_mfma_f32_16x16x32_bf16(
                    af[mi], bfr[ni], acc[mi][ni], 0, 0, 0);
    }

    // epilogue: C/D layout col=lane&15, row=(lane>>4)*4+reg  [verified m89/m91]
    const int fr   = lane & 15;
    const int frow = (lane >> 4) * 4;
    const long rowBase = (long)bRow * 128 + wr;
    const int  colBase = bCol * 128 + wc;
#pragma unroll
    for (int ni = 0; ni < 4; ++ni) {
        const int col = colBase + ni * 16 + fr;
        const float bi = bias[col];
#pragma unroll
        for (int mi = 0; mi < 4; ++mi) {
#pragma unroll
            for (int j = 0; j < 4; ++j) {
                float v = acc[mi][ni][j] + bi;
                if (ACT == 1)  // exact gelu
                    v = 0.5f * v * (1.0f + erff(v * 0.70710678118654752f));
                const long r = rowBase + mi * 16 + frow + j;
                C[r * (long)ldc + coff + col] = __float2bfloat16(v);
            }
        }
    }
}

// ---------------------------------------------------------------------------
// Attention over 9-token sequences within a CHUNK of batches.
// One 256-thread block per sequence; grid = nbatches*9.
// qkv: [rows, 1536] bf16 chunk-local (Q|K|V blocks). out: [rows, 512] local.
// branch: 0=row, 1=col, 2=box.
// ---------------------------------------------------------------------------
__global__ __launch_bounds__(256)
void attn9(const bf16* __restrict__ qkv, bf16* __restrict__ out, int branch)
{
    __shared__ __align__(16) bf16 sQKV[9 * 1536];
    __shared__ float sP[8 * 81];   // sP[h*81 + i*9 + j]
    __shared__ int sTok[9];
    const int tid = threadIdx.x;
    const int s = blockIdx.x;
    const int b = s / 9, g = s % 9;

    if (tid < 9) {
        const int p = tid;
        int cell;
        if (branch == 0)      cell = g * 9 + p;                                   // row
        else if (branch == 1) cell = p * 9 + g;                                   // col
        else                  cell = ((g / 3) * 3 + p / 3) * 9 + (g % 3) * 3 + (p % 3); // box
        sTok[p] = b * 81 + cell;
    }
    __syncthreads();

    // gather 9 x 1536 bf16 rows into LDS, 16B chunks
    for (int c = tid; c < 1728; c += 256) {
        const int p = c / 192;
        const int off = (c - p * 192) * 8;
        *(s8v*)(&sQKV[p * 1536 + off]) =
            *(const s8v*)(&qkv[(long)sTok[p] * 1536 + off]);
    }
    __syncthreads();

    // scores: 8 heads x 9 x 9 dots of length 64, scale 1/8
    for (int t = tid; t < 648; t += 256) {
        const int h = t / 81;
        const int r = t - h * 81;
        const int i = r / 9, j = r - (r / 9) * 9;
        const bf16* q = &sQKV[i * 1536 + h * 64];
        const bf16* k = &sQKV[j * 1536 + 512 + h * 64];
        float accd = 0.0f;
#pragma unroll
        for (int dc = 0; dc < 8; ++dc) {
            s8v qv = *(const s8v*)(q + dc * 8);
            s8v kv = *(const s8v*)(k + dc * 8);
#pragma unroll
            for (int e2 = 0; e2 < 8; ++e2)
                accd += bfs2f(qv[e2]) * bfs2f(kv[e2]);
        }
        sP[t] = accd * 0.125f;
    }
    __syncthreads();

    // softmax per (h,i) row of 9
    if (tid < 72) {
        float* row = &sP[tid * 9];
        float m = row[0];
#pragma unroll
        for (int j = 1; j < 9; ++j) m = fmaxf(m, row[j]);
        float sum = 0.f, e[9];
#pragma unroll
        for (int j = 0; j < 9; ++j) { e[j] = expf(row[j] - m); sum += e[j]; }
        const float inv = 1.0f / sum;
#pragma unroll
        for (int j = 0; j < 9; ++j) row[j] = e[j] * inv;
    }
    __syncthreads();

    // out[i, c] = sum_j P[h][i][j] * V[j][c],  h = c/64
    for (int t = tid; t < 576; t += 256) {
        const int i = t >> 6;
        const int c8 = (t & 63) * 8;
        const int h = (t & 63) >> 3;
        const float* prow = &sP[h * 81 + i * 9];
        float accv[8];
#pragma unroll
        for (int q2 = 0; q2 < 8; ++q2) accv[q2] = 0.f;
#pragma unroll
        for (int j = 0; j < 9; ++j) {
            const float p = prow[j];
            s8v vv = *(const s8v*)(&sQKV[j * 1536 + 1024 + c8]);
#pragma unroll
            for (int q2 = 0; q2 < 8; ++q2)
                accv[q2] += p * bfs2f(vv[q2]);
        }
        s8v ov;
#pragma unroll
        for (int q2 = 0; q2 < 8; ++q2) ov[q2] = f2bfs(accv[q2]);
        *(s8v*)(&out[(long)sTok[i] * 512 + c8]) = ov;
    }
}

// ---------------------------------------------------------------------------
// Residual + LayerNorm: out = LN(x + mixed) * gamma + beta, E=512.
// x fp32 (original input), mixed bf16, gamma/beta fp32, out fp32.
// One wave per row.
// ---------------------------------------------------------------------------
__global__ __launch_bounds__(256)
void ln_res(const float* __restrict__ x, const bf16* __restrict__ mixed,
            const float* __restrict__ gamma, const float* __restrict__ beta,
            float* __restrict__ out)
{
    const int tid = threadIdx.x;
    const int lane = tid & 63;
    const long row = (long)blockIdx.x * 4 + (tid >> 6);
    const long base = row * 512 + lane * 8;
    const float4 x0 = *(const float4*)(&x[base]);
    const float4 x1 = *(const float4*)(&x[base + 4]);
    const s8v mv = *(const s8v*)(&mixed[base]);
    float y[8];
    y[0] = x0.x + bfs2f(mv[0]); y[1] = x0.y + bfs2f(mv[1]);
    y[2] = x0.z + bfs2f(mv[2]); y[3] = x0.w + bfs2f(mv[3]);
    y[4] = x1.x + bfs2f(mv[4]); y[5] = x1.y + bfs2f(mv[5]);
    y[6] = x1.z + bfs2f(mv[6]); y[7] = x1.w + bfs2f(mv[7]);
    float sum = 0.f, sq = 0.f;
#pragma unroll
    for (int j = 0; j < 8; ++j) { sum += y[j]; sq += y[j] * y[j]; }
#pragma unroll
    for (int o = 32; o > 0; o >>= 1) {
        sum += __shfl_xor(sum, o, 64);
        sq  += __shfl_xor(sq, o, 64);
    }
    const float mean = sum * (1.f / 512.f);
    const float inv = rsqrtf(sq * (1.f / 512.f) - mean * mean + 1e-5f);
    const float4 g0 = *(const float4*)(&gamma[lane * 8]);
    const float4 g1 = *(const float4*)(&gamma[lane * 8 + 4]);
    const float4 b0 = *(const float4*)(&beta[lane * 8]);
    const float4 b1 = *(const float4*)(&beta[lane * 8 + 4]);
    float4 o0, o1;
    o0.x = (y[0] - mean) * inv * g0.x + b0.x;
    o0.y = (y[1] - mean) * inv * g0.y + b0.y;
    o0.z = (y[2] - mean) * inv * g0.z + b0.z;
    o0.w = (y[3] - mean) * inv * g0.w + b0.w;
    o1.x = (y[4] - mean) * inv * g1.x + b1.x;
    o1.y = (y[5] - mean) * inv * g1.y + b1.y;
    o1.z = (y[6] - mean) * inv * g1.z + b1.z;
    o1.w = (y[7] - mean) * inv * g1.w + b1.w;
    *(float4*)(&out[base]) = o0;
    *(float4*)(&out[base + 4]) = o1;
}

// ---------------------------------------------------------------------------
extern "C" void kernel_launch(void* const* d_in, const int* in_sizes, int n_in,
                              void* d_out, int out_size, void* d_ws, size_t ws_size,
                              hipStream_t stream)
{
    (void)in_sizes; (void)n_in; (void)out_size; (void)ws_size;
    const float* x     = (const float*)d_in[0];
    const float* b1f   = (const float*)d_in[14];
    const float* b2f   = (const float*)d_in[16];
    const float* gamma = (const float*)d_in[17];
    const float* beta  = (const float*)d_in[18];

    // ---- workspace layout (total 435,159,040 bytes) ----
    // [0, 254.8MB)   combined [82944x1536 bf16]; reused as mixed [82944x512 bf16] after MLP1
    // [254.8MB, +169.87MB) region R:
    //     qkvchunk  [20736x1536 bf16] = 63,700,992
    //     attnchunk [20736x512  bf16] = 21,233,664   (at R+63,700,992)
    //     xb        [82944x512  bf16] = 84,934,656   (at R+84,934,656)
    //     -> whole R reused as h [82944x1024 bf16] = 169,869,312 after attention phase
    // [424.67MB, +10.49MB) bf16 weights
    char* ws = (char*)d_ws;
    bf16* combined  = (bf16*)(ws);
    char* R         = ws + 254803968LL;
    bf16* qkvchunk  = (bf16*)(R);
    bf16* attnchunk = (bf16*)(R + 63700992LL);
    bf16* xb        = (bf16*)(R + 84934656LL);
    bf16* h         = (bf16*)(R);
    bf16* mixed     = (bf16*)(ws);
    char* wbase     = ws + 424673280LL;
    bf16* wqkv_b[3], *wo_b[3];
    long woff = 0;
    for (int i = 0; i < 3; ++i) { wqkv_b[i] = (bf16*)(wbase + woff); woff += 1572864; }
    for (int i = 0; i < 3; ++i) { wo_b[i]   = (bf16*)(wbase + woff); woff += 524288; }
    bf16* w1_b = (bf16*)(wbase + woff); woff += 3145728;
    bf16* w2_b = (bf16*)(wbase + woff); woff += 1048576;

    const dim3 blk(256, 1, 1);
    // fp32 -> bf16 conversions
    {
        long n4 = 42467328L / 4;
        cvt_f32_bf16<<<dim3((unsigned)((n4 + 255) / 256)), blk, 0, stream>>>(x, xb, n4);
        for (int i = 0; i < 3; ++i) {
            cvt_f32_bf16<<<dim3(768), blk, 0, stream>>>(
                (const float*)d_in[1 + i * 4], wqkv_b[i], 786432 / 4);
            cvt_f32_bf16<<<dim3(256), blk, 0, stream>>>(
                (const float*)d_in[3 + i * 4], wo_b[i], 262144 / 4);
        }
        cvt_f32_bf16<<<dim3(1536), blk, 0, stream>>>((const float*)d_in[13], w1_b, 1572864 / 4);
        cvt_f32_bf16<<<dim3(512), blk, 0, stream>>>((const float*)d_in[15], w2_b, 524288 / 4);
    }

    // attention phase: 3 branches x 4 chunks of 256 batches (20736 rows each)
    const long ROWS_C = 20736;
    for (int br = 0; br < 3; ++br) {
        const float* bqkv = (const float*)d_in[2 + br * 4];
        const float* bo   = (const float*)d_in[4 + br * 4];
        for (int c = 0; c < 4; ++c) {
            const bf16* xA = xb + c * ROWS_C * 512;
            // qkv = x_chunk @ wqkv^T + bqkv  [20736, 1536]
            gemm_bt<0><<<dim3(162, 12), blk, 0, stream>>>(xA, wqkv_b[br], bqkv, qkvchunk, 512, 1536, 0);
            // attention on 2304 sequences (chunk-local)
            attn9<<<dim3(2304), blk, 0, stream>>>(qkvchunk, attnchunk, br);
            // o-proj into combined[c-chunk rows, br*512 block]
            gemm_bt<0><<<dim3(162, 4), blk, 0, stream>>>(
                attnchunk, wo_b[br], bo, combined + c * ROWS_C * 1536, 512, 1536, br * 512);
        }
    }
    // h = gelu(combined @ w1^T + b1)  [82944, 1024]  (h overwrites R)
    gemm_bt<1><<<dim3(648, 8), blk, 0, stream>>>(combined, w1_b, b1f, h, 1536, 1024, 0);
    // mixed = h @ w2^T + b2  [82944, 512]  (mixed overwrites combined region)
    gemm_bt<0><<<dim3(648, 4), blk, 0, stream>>>(h, w2_b, b2f, mixed, 1024, 512, 0);
    // out = LayerNorm(x + mixed), fp32 out
    ln_res<<<dim3(20736), blk, 0, stream>>>(x, mixed, gamma, beta, (float*)d_out);
}

// Round 4
// 1927.062 us; speedup vs baseline: 1.1489x; 1.1489x over previous
//
#include <hip/hip_runtime.h>
#include <hip/hip_bf16.h>
#include <math.h>

typedef __hip_bfloat16 bf16;
typedef __attribute__((ext_vector_type(8))) short s8v;   // 8 x bf16 bits
typedef __attribute__((ext_vector_type(4))) short s4v;   // 4 x bf16 bits
typedef __attribute__((ext_vector_type(4))) float f4v;   // MFMA accumulator

static __device__ __forceinline__ float bfs2f(short s) {
    return __uint_as_float(((unsigned)(unsigned short)s) << 16);
}
static __device__ __forceinline__ short f2bfs(float f) {
    __hip_bfloat16 h = __float2bfloat16(f);
    return *reinterpret_cast<short*>(&h);
}

// ---------------------------------------------------------------------------
// fp32 -> bf16 conversion (vectorized x4).
// ---------------------------------------------------------------------------
__global__ __launch_bounds__(256)
void cvt_f32_bf16(const float* __restrict__ in, bf16* __restrict__ out, long n4)
{
    const long i = (long)blockIdx.x * 256 + threadIdx.x;
    if (i >= n4) return;
    const float4 v = reinterpret_cast<const float4*>(in)[i];
    s4v o;
    o[0] = f2bfs(v.x); o[1] = f2bfs(v.y); o[2] = f2bfs(v.z); o[3] = f2bfs(v.w);
    reinterpret_cast<s4v*>(out)[i] = o;
}

// ---------------------------------------------------------------------------
// fp32 [R x C] -> bf16 transposed [C x R], 32x32 LDS tiles. Grid (C/32, R/32),
// block 256 (32x8).
// ---------------------------------------------------------------------------
__global__ __launch_bounds__(256)
void cvt_t_f32_bf16(const float* __restrict__ in, bf16* __restrict__ out,
                    int R, int C)
{
    __shared__ float t[32][33];
    const int bx = blockIdx.x * 32;   // col tile of input
    const int by = blockIdx.y * 32;   // row tile of input
    const int tx = threadIdx.x & 31;
    const int ty = threadIdx.x >> 5;  // 0..7
#pragma unroll
    for (int r = ty; r < 32; r += 8)
        t[r][tx] = in[(long)(by + r) * C + bx + tx];
    __syncthreads();
#pragma unroll
    for (int r = ty; r < 32; r += 8)
        out[(long)(bx + r) * R + by + tx] = __float2bfloat16(t[tx][r]);
}

// ---------------------------------------------------------------------------
// b1p[m] = b1[m] + sum_br sum_k w1[m, br*512+k] * bo_br[k]   (all fp32)
// grid 4 x 256 = 1024 threads.
// ---------------------------------------------------------------------------
__global__ __launch_bounds__(256)
void fold_b1(const float* __restrict__ w1, const float* __restrict__ bo0,
             const float* __restrict__ bo1, const float* __restrict__ bo2,
             const float* __restrict__ b1, float* __restrict__ b1p)
{
    const int m = blockIdx.x * 256 + threadIdx.x;
    float s = b1[m];
    const float* w = w1 + (long)m * 1536;
    for (int k = 0; k < 512; ++k) s += w[k]         * bo0[k];
    for (int k = 0; k < 512; ++k) s += w[512 + k]   * bo1[k];
    for (int k = 0; k < 512; ++k) s += w[1024 + k]  * bo2[k];
    b1p[m] = s;
}

// ---------------------------------------------------------------------------
// GEMM: C[M,N](bf16) = act(A[M,K] @ B[N,K]^T + bias[N])
// m97 structure: 128x128 tile, BK=32, 256 threads (4 waves, 2x2 of 64x64),
// global_load_lds width-16 staging, mfma_f32_16x16x32_bf16.
// Grid: (N/128, M/128) -- N-dim FAST for A-panel L2 locality.
// A row stride lda, B row stride K (B is [N,K]), bias fp32 (nullable).
// Writes C[r*ldc + coff + n].  ACT: 0=none, 1=gelu(tanh approx).
// ---------------------------------------------------------------------------
template<int ACT>
__global__ __launch_bounds__(256)
void gemm_bt(const bf16* __restrict__ A, const bf16* __restrict__ B,
             const float* __restrict__ bias, bf16* __restrict__ C,
             int K, int lda, int ldc, int coff)
{
    __shared__ __align__(16) bf16 sA[128 * 32];
    __shared__ __align__(16) bf16 sB[128 * 32];
    const int tid  = threadIdx.x;
    const int lane = tid & 63;
    const int bCol = blockIdx.x;   // N fast
    const int bRow = blockIdx.y;
    const int wr = ((tid >> 7) & 1) * 64;
    const int wc = ((tid >> 6) & 1) * 64;

    f4v acc[4][4];
#pragma unroll
    for (int i = 0; i < 4; ++i)
#pragma unroll
        for (int j = 0; j < 4; ++j) acc[i][j] = (f4v)(0.0f);

    const int ldrow = tid >> 2;
    const int ldcol = (tid & 3) * 8;
    const bf16* Ab = A + (long)bRow * 128 * lda + (long)ldrow * lda + ldcol;
    const bf16* Bb = B + (long)bCol * 128 * K + (long)ldrow * K + ldcol;
    const int ldsWB = (tid & 192) * 16;
    char* sAc = (char*)sA;
    char* sBc = (char*)sB;

    const int nk = K >> 5;
    for (int kt = 0; kt < nk; ++kt) {
        const int k0 = kt << 5;
        __syncthreads();
#pragma unroll
        for (int p = 0; p < 2; ++p) {
            __builtin_amdgcn_global_load_lds(
                (const __attribute__((address_space(1))) unsigned int*)(Ab + (long)(p * 64) * lda + k0),
                (__attribute__((address_space(3))) unsigned int*)(sAc + p * 4096 + ldsWB),
                16, 0, 0);
            __builtin_amdgcn_global_load_lds(
                (const __attribute__((address_space(1))) unsigned int*)(Bb + (long)(p * 64) * K + k0),
                (__attribute__((address_space(3))) unsigned int*)(sBc + p * 4096 + ldsWB),
                16, 0, 0);
        }
        __syncthreads();
        const int fr  = lane & 15;
        const int kb8 = (lane >> 4) * 8;
        s8v af[4], bfr[4];
#pragma unroll
        for (int mi = 0; mi < 4; ++mi)
            af[mi] = *(const s8v*)(&sA[(wr + mi * 16 + fr) * 32 + kb8]);
#pragma unroll
        for (int ni = 0; ni < 4; ++ni)
            bfr[ni] = *(const s8v*)(&sB[(wc + ni * 16 + fr) * 32 + kb8]);
#pragma unroll
        for (int mi = 0; mi < 4; ++mi)
#pragma unroll
            for (int ni = 0; ni < 4; ++ni)
                acc[mi][ni] = __builtin_amdgcn_mfma_f32_16x16x32_bf16(
                    af[mi], bfr[ni], acc[mi][ni], 0, 0, 0);
    }

    // epilogue: C/D layout col=lane&15, row=(lane>>4)*4+reg  [verified m89/m91]
    const int fr   = lane & 15;
    const int frow = (lane >> 4) * 4;
    const long rowBase = (long)bRow * 128 + wr;
    const int  colBase = bCol * 128 + wc;
#pragma unroll
    for (int ni = 0; ni < 4; ++ni) {
        const int col = colBase + ni * 16 + fr;
        const float bi = bias ? bias[coff + col] : 0.0f;
#pragma unroll
        for (int mi = 0; mi < 4; ++mi) {
#pragma unroll
            for (int j = 0; j < 4; ++j) {
                float v = acc[mi][ni][j] + bi;
                if (ACT == 1) {  // gelu, tanh approx (max abs err ~7e-4)
                    const float u = v * (0.7978845608f + 0.0356774081f * v * v);
                    const float t = 1.0f - 2.0f / (__expf(2.0f * u) + 1.0f);
                    v = 0.5f * v * (1.0f + t);
                }
                const long r = rowBase + mi * 16 + frow + j;
                C[r * (long)ldc + coff + col] = __float2bfloat16(v);
            }
        }
    }
}

// ---------------------------------------------------------------------------
// Attention over 9-token sequences within a chunk, single branch.
// qkv: [20736, 1536] bf16 chunk-local (Q|K|V col blocks).
// Writes attention output (pre-o-proj) into attnall[82944,1536] at
// row = chunk_base + local token, col block = branch*512.
// ---------------------------------------------------------------------------
__global__ __launch_bounds__(256)
void attn9(const bf16* __restrict__ qkv, bf16* __restrict__ outg,
           int branch, long chunk_base)
{
    __shared__ __align__(16) bf16 sQKV[9 * 1536];
    __shared__ float sP[8 * 81];   // sP[h*81 + i*9 + j]
    __shared__ int sTok[9];
    const int tid = threadIdx.x;
    const int s = blockIdx.x;
    const int b = s / 9, g = s % 9;

    if (tid < 9) {
        const int p = tid;
        int cell;
        if (branch == 0)      cell = g * 9 + p;
        else if (branch == 1) cell = p * 9 + g;
        else                  cell = ((g / 3) * 3 + p / 3) * 9 + (g % 3) * 3 + (p % 3);
        sTok[p] = b * 81 + cell;
    }
    __syncthreads();

    for (int c = tid; c < 1728; c += 256) {
        const int p = c / 192;
        const int off = (c - p * 192) * 8;
        *(s8v*)(&sQKV[p * 1536 + off]) =
            *(const s8v*)(&qkv[(long)sTok[p] * 1536 + off]);
    }
    __syncthreads();

    for (int t = tid; t < 648; t += 256) {
        const int h = t / 81;
        const int r = t - h * 81;
        const int i = r / 9, j = r - (r / 9) * 9;
        const bf16* q = &sQKV[i * 1536 + h * 64];
        const bf16* k = &sQKV[j * 1536 + 512 + h * 64];
        float accd = 0.0f;
#pragma unroll
        for (int dc = 0; dc < 8; ++dc) {
            s8v qv = *(const s8v*)(q + dc * 8);
            s8v kv = *(const s8v*)(k + dc * 8);
#pragma unroll
            for (int e2 = 0; e2 < 8; ++e2)
                accd += bfs2f(qv[e2]) * bfs2f(kv[e2]);
        }
        sP[t] = accd * 0.125f;
    }
    __syncthreads();

    if (tid < 72) {
        float* row = &sP[tid * 9];
        float m = row[0];
#pragma unroll
        for (int j = 1; j < 9; ++j) m = fmaxf(m, row[j]);
        float sum = 0.f, e[9];
#pragma unroll
        for (int j = 0; j < 9; ++j) { e[j] = expf(row[j] - m); sum += e[j]; }
        const float inv = 1.0f / sum;
#pragma unroll
        for (int j = 0; j < 9; ++j) row[j] = e[j] * inv;
    }
    __syncthreads();

    for (int t = tid; t < 576; t += 256) {
        const int i = t >> 6;
        const int c8 = (t & 63) * 8;
        const int h = (t & 63) >> 3;
        const float* prow = &sP[h * 81 + i * 9];
        float accv[8];
#pragma unroll
        for (int q2 = 0; q2 < 8; ++q2) accv[q2] = 0.f;
#pragma unroll
        for (int j = 0; j < 9; ++j) {
            const float p = prow[j];
            s8v vv = *(const s8v*)(&sQKV[j * 1536 + 1024 + c8]);
#pragma unroll
            for (int q2 = 0; q2 < 8; ++q2)
                accv[q2] += p * bfs2f(vv[q2]);
        }
        s8v ov;
#pragma unroll
        for (int q2 = 0; q2 < 8; ++q2) ov[q2] = f2bfs(accv[q2]);
        *(s8v*)(&outg[(chunk_base + sTok[i]) * 1536 + branch * 512 + c8]) = ov;
    }
}

// ---------------------------------------------------------------------------
// Residual + LayerNorm: out = LN(x + mixed) * gamma + beta, E=512. fp32 I/O.
// ---------------------------------------------------------------------------
__global__ __launch_bounds__(256)
void ln_res(const float* __restrict__ x, const bf16* __restrict__ mixed,
            const float* __restrict__ gamma, const float* __restrict__ beta,
            float* __restrict__ out)
{
    const int tid = threadIdx.x;
    const int lane = tid & 63;
    const long row = (long)blockIdx.x * 4 + (tid >> 6);
    const long base = row * 512 + lane * 8;
    const float4 x0 = *(const float4*)(&x[base]);
    const float4 x1 = *(const float4*)(&x[base + 4]);
    const s8v mv = *(const s8v*)(&mixed[base]);
    float y[8];
    y[0] = x0.x + bfs2f(mv[0]); y[1] = x0.y + bfs2f(mv[1]);
    y[2] = x0.z + bfs2f(mv[2]); y[3] = x0.w + bfs2f(mv[3]);
    y[4] = x1.x + bfs2f(mv[4]); y[5] = x1.y + bfs2f(mv[5]);
    y[6] = x1.z + bfs2f(mv[6]); y[7] = x1.w + bfs2f(mv[7]);
    float sum = 0.f, sq = 0.f;
#pragma unroll
    for (int j = 0; j < 8; ++j) { sum += y[j]; sq += y[j] * y[j]; }
#pragma unroll
    for (int o = 32; o > 0; o >>= 1) {
        sum += __shfl_xor(sum, o, 64);
        sq  += __shfl_xor(sq, o, 64);
    }
    const float mean = sum * (1.f / 512.f);
    const float inv = rsqrtf(sq * (1.f / 512.f) - mean * mean + 1e-5f);
    const float4 g0 = *(const float4*)(&gamma[lane * 8]);
    const float4 g1 = *(const float4*)(&gamma[lane * 8 + 4]);
    const float4 b0 = *(const float4*)(&beta[lane * 8]);
    const float4 b1 = *(const float4*)(&beta[lane * 8 + 4]);
    float4 o0, o1;
    o0.x = (y[0] - mean) * inv * g0.x + b0.x;
    o0.y = (y[1] - mean) * inv * g0.y + b0.y;
    o0.z = (y[2] - mean) * inv * g0.z + b0.z;
    o0.w = (y[3] - mean) * inv * g0.w + b0.w;
    o1.x = (y[4] - mean) * inv * g1.x + b1.x;
    o1.y = (y[5] - mean) * inv * g1.y + b1.y;
    o1.z = (y[6] - mean) * inv * g1.z + b1.z;
    o1.w = (y[7] - mean) * inv * g1.w + b1.w;
    *(float4*)(&out[base]) = o0;
    *(float4*)(&out[base + 4]) = o1;
}

// ---------------------------------------------------------------------------
extern "C" void kernel_launch(void* const* d_in, const int* in_sizes, int n_in,
                              void* d_out, int out_size, void* d_ws, size_t ws_size,
                              hipStream_t stream)
{
    (void)in_sizes; (void)n_in; (void)out_size; (void)ws_size;
    const float* x     = (const float*)d_in[0];
    const float* w1f   = (const float*)d_in[13];
    const float* b1f   = (const float*)d_in[14];
    const float* b2f   = (const float*)d_in[16];
    const float* gamma = (const float*)d_in[17];
    const float* beta  = (const float*)d_in[18];

    // ---- workspace layout (total ~438.3 MB) ----
    // [0, 254.8MB)  attnall [82944x1536 bf16]; later mixed [82944x512] reuses
    // [254.8MB, +169.87MB) region R:
    //     qkvchunk [20736x1536 bf16] = 63,700,992
    //     xb       [82944x512  bf16] = 84,934,656   at R+63,700,992
    //     -> h [82944x1024 bf16] = 169,869,312 reuses all of R after attention
    // [424.67MB, ...) weights / precomputes
    char* ws = (char*)d_ws;
    bf16* attnall  = (bf16*)(ws);
    bf16* mixed    = (bf16*)(ws);
    char* R        = ws + 254803968LL;
    bf16* qkvchunk = (bf16*)(R);
    bf16* xb       = (bf16*)(R + 63700992LL);
    bf16* h        = (bf16*)(R);
    char* wb       = ws + 424673280LL;
    bf16* wqkv_b[3], *woT_b[3];
    long off = 0;
    for (int i = 0; i < 3; ++i) { wqkv_b[i] = (bf16*)(wb + off); off += 1572864; }
    for (int i = 0; i < 3; ++i) { woT_b[i]  = (bf16*)(wb + off); off += 524288; }
    bf16* w1_b = (bf16*)(wb + off); off += 3145728;
    bf16* w2_b = (bf16*)(wb + off); off += 1048576;
    bf16* Wp   = (bf16*)(wb + off); off += 3145728;
    float* b1p = (float*)(wb + off); off += 4096;

    const dim3 blk(256, 1, 1);

    // conversions
    cvt_f32_bf16<<<dim3(41472), blk, 0, stream>>>(x, xb, 10616832L);
    for (int i = 0; i < 3; ++i) {
        cvt_f32_bf16<<<dim3(768), blk, 0, stream>>>(
            (const float*)d_in[1 + i * 4], wqkv_b[i], 196608L);
        cvt_t_f32_bf16<<<dim3(16, 16), blk, 0, stream>>>(
            (const float*)d_in[3 + i * 4], woT_b[i], 512, 512);
    }
    cvt_f32_bf16<<<dim3(1536), blk, 0, stream>>>(w1f, w1_b, 393216L);
    cvt_f32_bf16<<<dim3(512), blk, 0, stream>>>((const float*)d_in[15], w2_b, 131072L);

    // bias fold: b1p = b1 + sum_br w1_br @ bo_br
    fold_b1<<<dim3(4), blk, 0, stream>>>(w1f, (const float*)d_in[4],
                                         (const float*)d_in[8], (const float*)d_in[12],
                                         b1f, b1p);

    // Wp[:, br*512+k] = (w1_br @ wo_br)[:, k]   -- M=1024, N=512, K=512
    for (int br = 0; br < 3; ++br)
        gemm_bt<0><<<dim3(4, 8), blk, 0, stream>>>(
            w1_b + br * 512, woT_b[br], nullptr, Wp, 512, 1536, 1536, br * 512);

    // attention phase: 4 chunks x 3 branches
    const long ROWS_C = 20736;
    for (int c = 0; c < 4; ++c) {
        const bf16* xA = xb + c * ROWS_C * 512;
        for (int br = 0; br < 3; ++br) {
            const float* bqkv = (const float*)d_in[2 + br * 4];
            // qkv = x_chunk @ wqkv^T + bqkv  [20736, 1536]
            gemm_bt<0><<<dim3(12, 162), blk, 0, stream>>>(
                xA, wqkv_b[br], bqkv, qkvchunk, 512, 512, 1536, 0);
            // attention -> attnall[:, br*512 block]
            attn9<<<dim3(2304), blk, 0, stream>>>(qkvchunk, attnall, br, c * ROWS_C);
        }
    }
    // h = gelu(attnall @ Wp^T + b1p)  [82944, 1024]
    gemm_bt<1><<<dim3(8, 648), blk, 0, stream>>>(attnall, Wp, b1p, h, 1536, 1536, 1024, 0);
    // mixed = h @ w2^T + b2  [82944, 512]
    gemm_bt<0><<<dim3(4, 648), blk, 0, stream>>>(h, w2_b, b2f, mixed, 1024, 1024, 512, 0);
    // out = LayerNorm(x + mixed), fp32
    ln_res<<<dim3(20736), blk, 0, stream>>>(x, mixed, gamma, beta, (float*)d_out);
}

// Round 5
// 1578.038 us; speedup vs baseline: 1.4030x; 1.2212x over previous
//
#include <hip/hip_runtime.h>
#include <hip/hip_bf16.h>
#include <math.h>

typedef __hip_bfloat16 bf16;
typedef __attribute__((ext_vector_type(8))) short s8v;   // 8 x bf16 bits
typedef __attribute__((ext_vector_type(4))) short s4v;   // 4 x bf16 bits
typedef __attribute__((ext_vector_type(4))) float f4v;   // MFMA accumulator

static __device__ __forceinline__ float bfs2f(short s) {
    return __uint_as_float(((unsigned)(unsigned short)s) << 16);
}
static __device__ __forceinline__ short f2bfs(float f) {
    __hip_bfloat16 h = __float2bfloat16(f);
    return *reinterpret_cast<short*>(&h);
}

// ---------------------------------------------------------------------------
// fp32 -> bf16 conversion (vectorized x4).
// ---------------------------------------------------------------------------
__global__ __launch_bounds__(256)
void cvt_f32_bf16(const float* __restrict__ in, bf16* __restrict__ out, long n4)
{
    const long i = (long)blockIdx.x * 256 + threadIdx.x;
    if (i >= n4) return;
    const float4 v = reinterpret_cast<const float4*>(in)[i];
    s4v o;
    o[0] = f2bfs(v.x); o[1] = f2bfs(v.y); o[2] = f2bfs(v.z); o[3] = f2bfs(v.w);
    reinterpret_cast<s4v*>(out)[i] = o;
}

// ---------------------------------------------------------------------------
// fp32 [R x C] -> bf16 transposed [C x R], 32x32 LDS tiles.
// ---------------------------------------------------------------------------
__global__ __launch_bounds__(256)
void cvt_t_f32_bf16(const float* __restrict__ in, bf16* __restrict__ out,
                    int R, int C)
{
    __shared__ float t[32][33];
    const int bx = blockIdx.x * 32;
    const int by = blockIdx.y * 32;
    const int tx = threadIdx.x & 31;
    const int ty = threadIdx.x >> 5;
#pragma unroll
    for (int r = ty; r < 32; r += 8)
        t[r][tx] = in[(long)(by + r) * C + bx + tx];
    __syncthreads();
#pragma unroll
    for (int r = ty; r < 32; r += 8)
        out[(long)(bx + r) * R + by + tx] = __float2bfloat16(t[tx][r]);
}

// ---------------------------------------------------------------------------
// b1p[m] = b1[m] + sum_br sum_k w1[m, br*512+k] * bo_br[k]   (fp32)
// ---------------------------------------------------------------------------
__global__ __launch_bounds__(256)
void fold_b1(const float* __restrict__ w1, const float* __restrict__ bo0,
             const float* __restrict__ bo1, const float* __restrict__ bo2,
             const float* __restrict__ b1, float* __restrict__ b1p)
{
    const int m = blockIdx.x * 256 + threadIdx.x;
    float s = b1[m];
    const float* w = w1 + (long)m * 1536;
    for (int k = 0; k < 512; ++k) s += w[k]        * bo0[k];
    for (int k = 0; k < 512; ++k) s += w[512 + k]  * bo1[k];
    for (int k = 0; k < 512; ++k) s += w[1024 + k] * bo2[k];
    b1p[m] = s;
}

// ---------------------------------------------------------------------------
// GEMM: C[M,N](bf16) = act(A[M,K] @ B[N,K]^T + bias[N])
// 128x128 tile, BK=64, 256 threads (2x2 waves), global_load_lds width-16,
// XOR bank-swizzle (chunk ^= row&7, pre-swizzled global source, rule #21),
// bijective XCD swizzle (requires gridDim.x*gridDim.y % 8 == 0).
// Grid (N/128, M/128). A stride lda, B is [N,K]. bias fp32 or null.
// Writes C[r*ldc + coff + col]. ACT: 0=none, 1=gelu(tanh approx).
// ---------------------------------------------------------------------------
template<int ACT>
__global__ __launch_bounds__(256)
void gemm_bt(const bf16* __restrict__ A, const bf16* __restrict__ B,
             const float* __restrict__ bias, bf16* __restrict__ C,
             int K, int lda, int ldc, int coff)
{
    __shared__ __align__(16) bf16 sA[128 * 64];
    __shared__ __align__(16) bf16 sB[128 * 64];
    const int tid  = threadIdx.x;
    const int lane = tid & 63;
    // XCD-chunked bijective block swizzle (XCD = linear bid % 8)
    const int nwg = gridDim.x * gridDim.y;
    const int bid = blockIdx.x + gridDim.x * blockIdx.y;
    const int sbid = (bid & 7) * (nwg >> 3) + (bid >> 3);
    const int bCol = sbid % gridDim.x;
    const int bRow = sbid / gridDim.x;
    const int wr = ((tid >> 7) & 1) * 64;
    const int wc = ((tid >> 6) & 1) * 64;

    f4v acc[4][4];
#pragma unroll
    for (int i = 0; i < 4; ++i)
#pragma unroll
        for (int j = 0; j < 4; ++j) acc[i][j] = (f4v)(0.0f);

    // staging: thread t -> LDS byte p*4096 + t*16 (linear dest),
    // logical (row = p*32 + t/8, chunk = t&7); source chunk pre-swizzled.
    const int srow = tid >> 3;                        // 0..31
    const int scol = ((tid & 7) ^ (srow & 7)) * 8;    // element offset in row
    const bf16* Ab = A + (long)(bRow * 128 + srow) * lda + scol;
    const bf16* Bb = B + (long)(bCol * 128 + srow) * K + scol;
    char* sAc = (char*)sA;
    char* sBc = (char*)sB;
    const int dst = tid * 16;

    const int fr = lane & 15;
    const int hi = lane >> 4;       // 0..3
    const int rx = fr & 7;          // row XOR bits for fragment reads

    const int nk = K >> 6;
    for (int kt = 0; kt < nk; ++kt) {
        const int k0 = kt << 6;
        __syncthreads();
#pragma unroll
        for (int p = 0; p < 4; ++p) {
            __builtin_amdgcn_global_load_lds(
                (const __attribute__((address_space(1))) unsigned int*)(Ab + (long)(p * 32) * lda + k0),
                (__attribute__((address_space(3))) unsigned int*)(sAc + p * 4096 + dst),
                16, 0, 0);
            __builtin_amdgcn_global_load_lds(
                (const __attribute__((address_space(1))) unsigned int*)(Bb + (long)(p * 32) * K + k0),
                (__attribute__((address_space(3))) unsigned int*)(sBc + p * 4096 + dst),
                16, 0, 0);
        }
        __syncthreads();
#pragma unroll
        for (int s = 0; s < 2; ++s) {
            const int co = ((s * 4 + hi) ^ rx) * 8;   // swizzled chunk offset
            s8v af[4], bfr[4];
#pragma unroll
            for (int mi = 0; mi < 4; ++mi)
                af[mi] = *(const s8v*)(&sA[(wr + mi * 16 + fr) * 64 + co]);
#pragma unroll
            for (int ni = 0; ni < 4; ++ni)
                bfr[ni] = *(const s8v*)(&sB[(wc + ni * 16 + fr) * 64 + co]);
#pragma unroll
            for (int mi = 0; mi < 4; ++mi)
#pragma unroll
                for (int ni = 0; ni < 4; ++ni)
                    acc[mi][ni] = __builtin_amdgcn_mfma_f32_16x16x32_bf16(
                        af[mi], bfr[ni], acc[mi][ni], 0, 0, 0);
        }
    }

    // epilogue: C/D layout col=lane&15, row=(lane>>4)*4+reg  [verified m89/m91]
    const int frow = hi * 4;
    const long rowBase = (long)bRow * 128 + wr;
    const int  colBase = bCol * 128 + wc;
#pragma unroll
    for (int ni = 0; ni < 4; ++ni) {
        const int col = colBase + ni * 16 + fr;
        const float bi = bias ? bias[coff + col] : 0.0f;
#pragma unroll
        for (int mi = 0; mi < 4; ++mi) {
#pragma unroll
            for (int j = 0; j < 4; ++j) {
                float v = acc[mi][ni][j] + bi;
                if (ACT == 1) {  // gelu, tanh approx (max abs err ~7e-4)
                    const float u = v * (0.7978845608f + 0.0356774081f * v * v);
                    const float t = 1.0f - 2.0f / (__expf(2.0f * u) + 1.0f);
                    v = 0.5f * v * (1.0f + t);
                }
                const long r = rowBase + mi * 16 + frow + j;
                C[r * (long)ldc + coff + col] = __float2bfloat16(v);
            }
        }
    }
}

// ---------------------------------------------------------------------------
// Attention over 9-token sequences. qkv3: [20736, 4608] bf16 chunk-local
// (branch-major: br*1536 + {Q|K|V}*512). blockIdx.y = branch.
// Writes pre-o-proj output into attnall[82944,1536] col block br*512.
// ---------------------------------------------------------------------------
__global__ __launch_bounds__(256)
void attn9(const bf16* __restrict__ qkv, bf16* __restrict__ outg,
           long chunk_base)
{
    __shared__ __align__(16) bf16 sQKV[9 * 1536];
    __shared__ float sP[8 * 81];   // sP[h*81 + i*9 + j]
    __shared__ int sTok[9];
    const int tid = threadIdx.x;
    const int branch = blockIdx.y;
    // XCD swizzle on x (2304 % 8 == 0; y contributes 0 mod 8 to linear bid)
    const int bx = blockIdx.x;
    const int s = (bx & 7) * (2304 >> 3) + (bx >> 3);
    const int b = s / 9, g = s % 9;

    if (tid < 9) {
        const int p = tid;
        int cell;
        if (branch == 0)      cell = g * 9 + p;
        else if (branch == 1) cell = p * 9 + g;
        else                  cell = ((g / 3) * 3 + p / 3) * 9 + (g % 3) * 3 + (p % 3);
        sTok[p] = b * 81 + cell;
    }
    __syncthreads();

    const long brOff = (long)branch * 1536;
    for (int c = tid; c < 1728; c += 256) {
        const int p = c / 192;
        const int off = (c - p * 192) * 8;
        *(s8v*)(&sQKV[p * 1536 + off]) =
            *(const s8v*)(&qkv[(long)sTok[p] * 4608 + brOff + off]);
    }
    __syncthreads();

    for (int t = tid; t < 648; t += 256) {
        const int h = t / 81;
        const int r = t - h * 81;
        const int i = r / 9, j = r - (r / 9) * 9;
        const bf16* q = &sQKV[i * 1536 + h * 64];
        const bf16* k = &sQKV[j * 1536 + 512 + h * 64];
        float accd = 0.0f;
#pragma unroll
        for (int dc = 0; dc < 8; ++dc) {
            s8v qv = *(const s8v*)(q + dc * 8);
            s8v kv = *(const s8v*)(k + dc * 8);
#pragma unroll
            for (int e2 = 0; e2 < 8; ++e2)
                accd += bfs2f(qv[e2]) * bfs2f(kv[e2]);
        }
        sP[t] = accd * 0.125f;
    }
    __syncthreads();

    if (tid < 72) {
        float* row = &sP[tid * 9];
        float m = row[0];
#pragma unroll
        for (int j = 1; j < 9; ++j) m = fmaxf(m, row[j]);
        float sum = 0.f, e[9];
#pragma unroll
        for (int j = 0; j < 9; ++j) { e[j] = expf(row[j] - m); sum += e[j]; }
        const float inv = 1.0f / sum;
#pragma unroll
        for (int j = 0; j < 9; ++j) row[j] = e[j] * inv;
    }
    __syncthreads();

    for (int t = tid; t < 576; t += 256) {
        const int i = t >> 6;
        const int c8 = (t & 63) * 8;
        const int h = (t & 63) >> 3;
        const float* prow = &sP[h * 81 + i * 9];
        float accv[8];
#pragma unroll
        for (int q2 = 0; q2 < 8; ++q2) accv[q2] = 0.f;
#pragma unroll
        for (int j = 0; j < 9; ++j) {
            const float p = prow[j];
            s8v vv = *(const s8v*)(&sQKV[j * 1536 + 1024 + c8]);
#pragma unroll
            for (int q2 = 0; q2 < 8; ++q2)
                accv[q2] += p * bfs2f(vv[q2]);
        }
        s8v ov;
#pragma unroll
        for (int q2 = 0; q2 < 8; ++q2) ov[q2] = f2bfs(accv[q2]);
        *(s8v*)(&outg[(chunk_base + sTok[i]) * 1536 + branch * 512 + c8]) = ov;
    }
}

// ---------------------------------------------------------------------------
// Residual + LayerNorm: out = LN(x + mixed) * gamma + beta, E=512. fp32 I/O.
// ---------------------------------------------------------------------------
__global__ __launch_bounds__(256)
void ln_res(const float* __restrict__ x, const bf16* __restrict__ mixed,
            const float* __restrict__ gamma, const float* __restrict__ beta,
            float* __restrict__ out)
{
    const int tid = threadIdx.x;
    const int lane = tid & 63;
    const long row = (long)blockIdx.x * 4 + (tid >> 6);
    const long base = row * 512 + lane * 8;
    const float4 x0 = *(const float4*)(&x[base]);
    const float4 x1 = *(const float4*)(&x[base + 4]);
    const s8v mv = *(const s8v*)(&mixed[base]);
    float y[8];
    y[0] = x0.x + bfs2f(mv[0]); y[1] = x0.y + bfs2f(mv[1]);
    y[2] = x0.z + bfs2f(mv[2]); y[3] = x0.w + bfs2f(mv[3]);
    y[4] = x1.x + bfs2f(mv[4]); y[5] = x1.y + bfs2f(mv[5]);
    y[6] = x1.z + bfs2f(mv[6]); y[7] = x1.w + bfs2f(mv[7]);
    float sum = 0.f, sq = 0.f;
#pragma unroll
    for (int j = 0; j < 8; ++j) { sum += y[j]; sq += y[j] * y[j]; }
#pragma unroll
    for (int o = 32; o > 0; o >>= 1) {
        sum += __shfl_xor(sum, o, 64);
        sq  += __shfl_xor(sq, o, 64);
    }
    const float mean = sum * (1.f / 512.f);
    const float inv = rsqrtf(sq * (1.f / 512.f) - mean * mean + 1e-5f);
    const float4 g0 = *(const float4*)(&gamma[lane * 8]);
    const float4 g1 = *(const float4*)(&gamma[lane * 8 + 4]);
    const float4 b0 = *(const float4*)(&beta[lane * 8]);
    const float4 b1 = *(const float4*)(&beta[lane * 8 + 4]);
    float4 o0, o1;
    o0.x = (y[0] - mean) * inv * g0.x + b0.x;
    o0.y = (y[1] - mean) * inv * g0.y + b0.y;
    o0.z = (y[2] - mean) * inv * g0.z + b0.z;
    o0.w = (y[3] - mean) * inv * g0.w + b0.w;
    o1.x = (y[4] - mean) * inv * g1.x + b1.x;
    o1.y = (y[5] - mean) * inv * g1.y + b1.y;
    o1.z = (y[6] - mean) * inv * g1.z + b1.z;
    o1.w = (y[7] - mean) * inv * g1.w + b1.w;
    *(float4*)(&out[base]) = o0;
    *(float4*)(&out[base + 4]) = o1;
}

// ---------------------------------------------------------------------------
extern "C" void kernel_launch(void* const* d_in, const int* in_sizes, int n_in,
                              void* d_out, int out_size, void* d_ws, size_t ws_size,
                              hipStream_t stream)
{
    (void)in_sizes; (void)n_in; (void)out_size; (void)ws_size;
    const float* x     = (const float*)d_in[0];
    const float* w1f   = (const float*)d_in[13];
    const float* b1f   = (const float*)d_in[14];
    const float* b2f   = (const float*)d_in[16];
    const float* gamma = (const float*)d_in[17];
    const float* beta  = (const float*)d_in[18];

    // ---- workspace layout (total ~543 MB; proven-safe < 594.5 MB) ----
    // [0, 254.8MB)   attnall [82944x1536 bf16]; later mixed reuses
    // [254.8MB, +276.0MB) region R:
    //     qkv3chunk [20736x4608 bf16] = 191,102,976
    //     xb        [82944x512  bf16] =  84,934,656  at R+191,102,976
    //     -> h [82944x1024 bf16] = 169,869,312 reuses R after attention
    // [530.8MB, ...) weights / precomputes (~12.1 MB)
    char* ws = (char*)d_ws;
    bf16* attnall   = (bf16*)(ws);
    bf16* mixed     = (bf16*)(ws);
    char* R         = ws + 254803968LL;
    bf16* qkv3chunk = (bf16*)(R);
    bf16* xb        = (bf16*)(R + 191102976LL);
    bf16* h         = (bf16*)(R);
    char* wb        = ws + 530841600LL;
    long off = 0;
    bf16* wqkv3_b = (bf16*)(wb + off); off += 4718592;   // [4608 x 512]
    bf16* woT_b[3];
    for (int i = 0; i < 3; ++i) { woT_b[i] = (bf16*)(wb + off); off += 524288; }
    bf16* w1_b  = (bf16*)(wb + off); off += 3145728;
    bf16* w2_b  = (bf16*)(wb + off); off += 1048576;
    bf16* Wp    = (bf16*)(wb + off); off += 3145728;
    float* b1p  = (float*)(wb + off); off += 4096;
    float* bqkv3 = (float*)(wb + off); off += 18432;     // [4608] fp32

    const dim3 blk(256, 1, 1);

    // conversions
    cvt_f32_bf16<<<dim3(41472), blk, 0, stream>>>(x, xb, 10616832L);
    for (int i = 0; i < 3; ++i) {
        cvt_f32_bf16<<<dim3(768), blk, 0, stream>>>(
            (const float*)d_in[1 + i * 4], wqkv3_b + (long)i * 786432, 196608L);
        cvt_t_f32_bf16<<<dim3(16, 16), blk, 0, stream>>>(
            (const float*)d_in[3 + i * 4], woT_b[i], 512, 512);
        hipMemcpyAsync(bqkv3 + i * 1536, d_in[2 + i * 4], 1536 * sizeof(float),
                       hipMemcpyDeviceToDevice, stream);
    }
    cvt_f32_bf16<<<dim3(1536), blk, 0, stream>>>(w1f, w1_b, 393216L);
    cvt_f32_bf16<<<dim3(512), blk, 0, stream>>>((const float*)d_in[15], w2_b, 131072L);

    // bias fold: b1p = b1 + sum_br w1_br @ bo_br
    fold_b1<<<dim3(4), blk, 0, stream>>>(w1f, (const float*)d_in[4],
                                         (const float*)d_in[8], (const float*)d_in[12],
                                         b1f, b1p);

    // Wp[:, br*512+k] = (w1_br @ wo_br)[:, k]   M=1024, N=512, K=512
    for (int br = 0; br < 3; ++br)
        gemm_bt<0><<<dim3(4, 8), blk, 0, stream>>>(
            w1_b + br * 512, woT_b[br], nullptr, Wp, 512, 1536, 1536, br * 512);

    // attention phase: 4 chunks of 256 batches (20736 rows)
    const long ROWS_C = 20736;
    for (int c = 0; c < 4; ++c) {
        const bf16* xA = xb + c * ROWS_C * 512;
        // qkv3 = x_chunk @ wqkv3^T + bqkv3   [20736, 4608]
        gemm_bt<0><<<dim3(36, 162), blk, 0, stream>>>(
            xA, wqkv3_b, bqkv3, qkv3chunk, 512, 512, 4608, 0);
        // attention, all 3 branches -> attnall
        attn9<<<dim3(2304, 3), blk, 0, stream>>>(qkv3chunk, attnall, c * ROWS_C);
    }
    // h = gelu(attnall @ Wp^T + b1p)  [82944, 1024]
    gemm_bt<1><<<dim3(8, 648), blk, 0, stream>>>(attnall, Wp, b1p, h, 1536, 1536, 1024, 0);
    // mixed = h @ w2^T + b2  [82944, 512]
    gemm_bt<0><<<dim3(4, 648), blk, 0, stream>>>(h, w2_b, b2f, mixed, 1024, 1024, 512, 0);
    // out = LayerNorm(x + mixed), fp32
    ln_res<<<dim3(20736), blk, 0, stream>>>(x, mixed, gamma, beta, (float*)d_out);
}